// Round 2
// baseline (4244.406 us; speedup 1.0000x reference)
//
#include <hip/hip_runtime.h>

#define DIMC 1536
#define NQKV 4608
#define NH   12
#define HD   128
#define NTOK 2304
#define SCTX 256
#define SIN  2048
#define BATCH 2

// ---------------------------------------------------------------------------
// Generic fp32 GEMM with bias: C[cmap(r)][n] = sum_k A[amap(r)][k] * W[k][n] + bias[n]
// amap(r) = (r/S)*aStr + aOff + r%S ; cmap(r) = (r/S)*cStr + cOff + r%S
// A pitch = K, C pitch = N. M%64==0, N%64==0, K%32==0 (all true here).
// ---------------------------------------------------------------------------
#define BM 64
#define BN 64
#define BK 32

__global__ __launch_bounds__(256) void gemm_bias(
    const float* __restrict__ A, const float* __restrict__ W,
    const float* __restrict__ bias, float* __restrict__ C,
    int M, int N, int K, int S, int aStr, int aOff, int cStr, int cOff)
{
    __shared__ float As[BM][BK + 4];
    __shared__ float Bs[BK][BN + 4];

    int tid = threadIdx.x;
    int bm = blockIdx.y * BM;
    int bn = blockIdx.x * BN;
    int tx = tid & 15, ty = tid >> 4;

    // A staging: each thread loads 8 contiguous floats (two float4)
    int arow = tid >> 2;            // 0..63
    int acol = (tid & 3) * 8;       // 0,8,16,24
    int r = bm + arow;
    size_t aphys = ((size_t)((r / S) * aStr + aOff + (r % S))) * (size_t)K;

    // B staging: rows 0..31, 8 cols per thread
    int brow = tid >> 3;            // 0..31
    int bcol = (tid & 7) * 8;       // 0..56

    float acc[4][4] = {{0.f}};

    for (int k0 = 0; k0 < K; k0 += BK) {
        const float4* a4 = (const float4*)(A + aphys + k0 + acol);
        float4 av0 = a4[0], av1 = a4[1];
        const float4* b4 = (const float4*)(W + (size_t)(k0 + brow) * N + bn + bcol);
        float4 bv0 = b4[0], bv1 = b4[1];
        As[arow][acol + 0] = av0.x; As[arow][acol + 1] = av0.y;
        As[arow][acol + 2] = av0.z; As[arow][acol + 3] = av0.w;
        As[arow][acol + 4] = av1.x; As[arow][acol + 5] = av1.y;
        As[arow][acol + 6] = av1.z; As[arow][acol + 7] = av1.w;
        Bs[brow][bcol + 0] = bv0.x; Bs[brow][bcol + 1] = bv0.y;
        Bs[brow][bcol + 2] = bv0.z; Bs[brow][bcol + 3] = bv0.w;
        Bs[brow][bcol + 4] = bv1.x; Bs[brow][bcol + 5] = bv1.y;
        Bs[brow][bcol + 6] = bv1.z; Bs[brow][bcol + 7] = bv1.w;
        __syncthreads();
        #pragma unroll
        for (int kk = 0; kk < BK; ++kk) {
            float a0 = As[ty*4+0][kk], a1 = As[ty*4+1][kk];
            float a2 = As[ty*4+2][kk], a3 = As[ty*4+3][kk];
            float b0 = Bs[kk][tx*4+0], b1 = Bs[kk][tx*4+1];
            float b2 = Bs[kk][tx*4+2], b3 = Bs[kk][tx*4+3];
            acc[0][0] += a0*b0; acc[0][1] += a0*b1; acc[0][2] += a0*b2; acc[0][3] += a0*b3;
            acc[1][0] += a1*b0; acc[1][1] += a1*b1; acc[1][2] += a1*b2; acc[1][3] += a1*b3;
            acc[2][0] += a2*b0; acc[2][1] += a2*b1; acc[2][2] += a2*b2; acc[2][3] += a2*b3;
            acc[3][0] += a3*b0; acc[3][1] += a3*b1; acc[3][2] += a3*b2; acc[3][3] += a3*b3;
        }
        __syncthreads();
    }

    float bsv[4];
    #pragma unroll
    for (int j = 0; j < 4; ++j) bsv[j] = bias[bn + tx*4 + j];
    #pragma unroll
    for (int i = 0; i < 4; ++i) {
        int r2 = bm + ty*4 + i;
        size_t crow = (size_t)((r2 / S) * cStr + cOff + (r2 % S));
        float* cp = C + crow * (size_t)N + bn + tx*4;
        #pragma unroll
        for (int j = 0; j < 4; ++j) cp[j] = acc[i][j] + bsv[j];
    }
}

// ---------------------------------------------------------------------------
// Per-token RMS norm (over full 1536) + per-element scale + RoPE + pack into
// Q[b,h,n,d], Kt[b,h,d,n], V[b,h,n,d] (fp32).
// ---------------------------------------------------------------------------
__global__ __launch_bounds__(256) void rms_rope_pack(
    const float* __restrict__ QKV,
    const float* __restrict__ qs_in, const float* __restrict__ ks_in,
    const float* __restrict__ qs_ctx, const float* __restrict__ ks_ctx,
    float* __restrict__ Q, float* __restrict__ Kt, float* __restrict__ V)
{
    __shared__ float qrow[DIMC];
    __shared__ float krow[DIMC];
    __shared__ float rq[4], rk[4];

    int token = blockIdx.x;          // 0..2*2304-1
    int b = token / NTOK;
    int p = token % NTOK;
    bool is_ctx = (p < SCTX);
    const float* qs = is_ctx ? qs_ctx : qs_in;
    const float* ks = is_ctx ? ks_ctx : ks_in;

    int t = threadIdx.x;
    const float* row = QKV + (size_t)token * NQKV;

    float ssq_q = 0.f, ssq_k = 0.f;
    #pragma unroll
    for (int i = 0; i < 6; ++i) {
        int c = t + 256 * i;
        float q = row[c];
        float k = row[DIMC + c];
        qrow[c] = q; krow[c] = k;
        ssq_q += q * q; ssq_k += k * k;
    }
    // wave reduce (width 64) then cross-wave via LDS
    for (int o = 32; o > 0; o >>= 1) {
        ssq_q += __shfl_down(ssq_q, o);
        ssq_k += __shfl_down(ssq_k, o);
    }
    if ((t & 63) == 0) { rq[t >> 6] = ssq_q; rk[t >> 6] = ssq_k; }
    __syncthreads();
    float sq = rq[0] + rq[1] + rq[2] + rq[3];
    float sk = rk[0] + rk[1] + rk[2] + rk[3];
    float invq = rsqrtf(sq * (1.0f / DIMC) + 1e-6f);
    float invk = rsqrtf(sk * (1.0f / DIMC) + 1e-6f);

    #pragma unroll
    for (int i = 0; i < 6; ++i) {
        int c = t + 256 * i;
        int h = c >> 7, d = c & 127;
        int j = d & 63;
        float inv_freq = powf(10000.0f, -(float)j * (1.0f / 64.0f));
        float ang = (float)p * inv_freq;
        float sn, cs;
        sincosf(ang, &sn, &cs);
        int pc = (d < 64) ? (c + 64) : (c - 64);

        float self_q = qrow[c]  * invq * qs[c];
        float part_q = qrow[pc] * invq * qs[pc];
        float qo = (d < 64) ? (self_q * cs - part_q * sn)
                            : (self_q * cs + part_q * sn);

        float self_k = krow[c]  * invk * ks[c];
        float part_k = krow[pc] * invk * ks[pc];
        float ko = (d < 64) ? (self_k * cs - part_k * sn)
                            : (self_k * cs + part_k * sn);

        float v = row[2 * DIMC + c];

        size_t qi  = ((size_t)(b * NH + h) * NTOK + p) * HD + d;
        size_t kti = ((size_t)(b * NH + h) * HD + d) * NTOK + p;
        Q[qi]   = qo;
        Kt[kti] = ko;
        V[qi]   = v;
    }
}

// ---------------------------------------------------------------------------
// Attention: one block (128 threads) per (b, h, 4 queries). Exact softmax.
// ---------------------------------------------------------------------------
#define QB 4
__global__ __launch_bounds__(128) void attn_kernel(
    const float* __restrict__ Q, const float* __restrict__ Kt,
    const float* __restrict__ V, float* __restrict__ O)
{
    __shared__ float qs_l[QB][HD];
    __shared__ float sc[QB][NTOK];
    __shared__ float red[2][QB];

    int t = threadIdx.x;
    int idx = blockIdx.x;
    int g  = idx % (NTOK / QB);
    int bh = idx / (NTOK / QB);
    int b = bh / NH, h = bh % NH;
    int p0 = g * QB;

    const float scale = 0.08838834764831845f;  // 1/sqrt(128)
    #pragma unroll
    for (int qq = 0; qq < QB; ++qq)
        qs_l[qq][t] = Q[((size_t)bh * NTOK + p0 + qq) * HD + t] * scale;
    __syncthreads();

    // ---- scores: each thread owns keys j = m*128 + t ----
    const float* KtB = Kt + (size_t)bh * HD * NTOK;
    float lmax[QB] = {-1e30f, -1e30f, -1e30f, -1e30f};
    for (int m = 0; m < NTOK / 128; ++m) {
        int j = m * 128 + t;
        float s0 = 0.f, s1 = 0.f, s2 = 0.f, s3 = 0.f;
        #pragma unroll 8
        for (int d = 0; d < HD; ++d) {
            float kd = KtB[(size_t)d * NTOK + j];
            s0 += qs_l[0][d] * kd;
            s1 += qs_l[1][d] * kd;
            s2 += qs_l[2][d] * kd;
            s3 += qs_l[3][d] * kd;
        }
        sc[0][j] = s0; sc[1][j] = s1; sc[2][j] = s2; sc[3][j] = s3;
        lmax[0] = fmaxf(lmax[0], s0); lmax[1] = fmaxf(lmax[1], s1);
        lmax[2] = fmaxf(lmax[2], s2); lmax[3] = fmaxf(lmax[3], s3);
    }
    #pragma unroll
    for (int qq = 0; qq < QB; ++qq)
        for (int o = 32; o > 0; o >>= 1)
            lmax[qq] = fmaxf(lmax[qq], __shfl_down(lmax[qq], o));
    if ((t & 63) == 0) {
        #pragma unroll
        for (int qq = 0; qq < QB; ++qq) red[t >> 6][qq] = lmax[qq];
    }
    __syncthreads();
    float gmax[QB];
    #pragma unroll
    for (int qq = 0; qq < QB; ++qq) gmax[qq] = fmaxf(red[0][qq], red[1][qq]);
    __syncthreads();   // red about to be reused for sums

    // ---- exp + sum (each thread exps only the j's it wrote) ----
    float lsum[QB] = {0.f, 0.f, 0.f, 0.f};
    for (int m = 0; m < NTOK / 128; ++m) {
        int j = m * 128 + t;
        #pragma unroll
        for (int qq = 0; qq < QB; ++qq) {
            float e = __expf(sc[qq][j] - gmax[qq]);
            sc[qq][j] = e;
            lsum[qq] += e;
        }
    }
    #pragma unroll
    for (int qq = 0; qq < QB; ++qq)
        for (int o = 32; o > 0; o >>= 1)
            lsum[qq] += __shfl_down(lsum[qq], o);
    if ((t & 63) == 0) {
        #pragma unroll
        for (int qq = 0; qq < QB; ++qq) red[t >> 6][qq] = lsum[qq];
    }
    __syncthreads();   // also makes all sc[][] exp writes visible
    float inv[QB];
    #pragma unroll
    for (int qq = 0; qq < QB; ++qq) inv[qq] = 1.0f / (red[0][qq] + red[1][qq]);

    // ---- PV: thread t owns output dim d = t ----
    const float* Vb = V + (size_t)bh * NTOK * HD + t;
    float acc[QB] = {0.f, 0.f, 0.f, 0.f};
    #pragma unroll 8
    for (int j = 0; j < NTOK; ++j) {
        float v = Vb[(size_t)j * HD];
        acc[0] += sc[0][j] * v;
        acc[1] += sc[1][j] * v;
        acc[2] += sc[2][j] * v;
        acc[3] += sc[3][j] * v;
    }
    #pragma unroll
    for (int qq = 0; qq < QB; ++qq)
        O[((size_t)b * NTOK + p0 + qq) * DIMC + h * HD + t] = acc[qq] * inv[qq];
}

// ---------------------------------------------------------------------------
extern "C" void kernel_launch(void* const* d_in, const int* in_sizes, int n_in,
                              void* d_out, int out_size, void* d_ws, size_t ws_size,
                              hipStream_t stream)
{
    const float* input     = (const float*)d_in[0];
    const float* context   = (const float*)d_in[1];
    const float* W_qkv_in  = (const float*)d_in[2];
    const float* b_qkv_in  = (const float*)d_in[3];
    const float* W_qkv_ctx = (const float*)d_in[4];
    const float* b_qkv_ctx = (const float*)d_in[5];
    const float* qs_in     = (const float*)d_in[6];
    const float* ks_in     = (const float*)d_in[7];
    const float* qs_ctx    = (const float*)d_in[8];
    const float* ks_ctx    = (const float*)d_in[9];
    const float* W_out_in  = (const float*)d_in[10];
    const float* b_out_in  = (const float*)d_in[11];
    const float* W_out_ctx = (const float*)d_in[12];
    const float* b_out_ctx = (const float*)d_in[13];
    float* out = (float*)d_out;

    char* ws = (char*)d_ws;
    float* QKV = (float*)ws;                          // [2*2304, 4608] fp32 (84.9 MB)
    float* O   = (float*)ws;                          // overlaps QKV (dead by then)
    size_t off = (size_t)BATCH * NTOK * NQKV * sizeof(float);
    float* Q  = (float*)(ws + off);                   // [2,12,2304,128]
    float* Kt = Q  + (size_t)BATCH * NH * NTOK * HD;  // [2,12,128,2304]
    float* V  = Kt + (size_t)BATCH * NH * NTOK * HD;  // [2,12,2304,128]

    dim3 blk(256);

    // QKV projections (scatter into combined ctx-first token order)
    gemm_bias<<<dim3(NQKV / BN, (BATCH * SIN) / BM), blk, 0, stream>>>(
        input, W_qkv_in, b_qkv_in, QKV,
        BATCH * SIN, NQKV, DIMC, SIN, SIN, 0, NTOK, SCTX);
    gemm_bias<<<dim3(NQKV / BN, (BATCH * SCTX) / BM), blk, 0, stream>>>(
        context, W_qkv_ctx, b_qkv_ctx, QKV,
        BATCH * SCTX, NQKV, DIMC, SCTX, SCTX, 0, NTOK, 0);

    // RMS norm + scale + RoPE + head pack
    rms_rope_pack<<<BATCH * NTOK, 256, 0, stream>>>(
        QKV, qs_in, ks_in, qs_ctx, ks_ctx, Q, Kt, V);

    // attention
    attn_kernel<<<BATCH * NH * (NTOK / QB), 128, 0, stream>>>(Q, Kt, V, O);

    // output projections (gather rows from combined order)
    gemm_bias<<<dim3(DIMC / BN, (BATCH * SIN) / BM), blk, 0, stream>>>(
        O, W_out_in, b_out_in, out,
        BATCH * SIN, DIMC, DIMC, SIN, NTOK, SCTX, SIN, 0);
    gemm_bias<<<dim3(DIMC / BN, (BATCH * SCTX) / BM), blk, 0, stream>>>(
        O, W_out_ctx, b_out_ctx, out + (size_t)BATCH * SIN * DIMC,
        BATCH * SCTX, DIMC, DIMC, SCTX, NTOK, 0, SCTX, 0);
}

// Round 3
// 1620.062 us; speedup vs baseline: 2.6199x; 2.6199x over previous
//
#include <hip/hip_runtime.h>
#include <hip/hip_bf16.h>

typedef __hip_bfloat16 bf16;
typedef __attribute__((ext_vector_type(8))) short short8;
typedef __attribute__((ext_vector_type(4))) float f32x4;

#define DIMC 1536
#define NQKV 4608
#define NH   12
#define HD   128
#define NTOK 2304
#define SCTX 256
#define SIN  2048
#define BATCH 2

// ---------------------------------------------------------------------------
// Generic fp32 GEMM with bias (unchanged from round 1).
// ---------------------------------------------------------------------------
#define BM 64
#define BN 64
#define BK 32

__global__ __launch_bounds__(256) void gemm_bias(
    const float* __restrict__ A, const float* __restrict__ W,
    const float* __restrict__ bias, float* __restrict__ C,
    int M, int N, int K, int S, int aStr, int aOff, int cStr, int cOff)
{
    __shared__ float As[BM][BK + 4];
    __shared__ float Bs[BK][BN + 4];

    int tid = threadIdx.x;
    int bm = blockIdx.y * BM;
    int bn = blockIdx.x * BN;
    int tx = tid & 15, ty = tid >> 4;

    int arow = tid >> 2;
    int acol = (tid & 3) * 8;
    int r = bm + arow;
    size_t aphys = ((size_t)((r / S) * aStr + aOff + (r % S))) * (size_t)K;

    int brow = tid >> 3;
    int bcol = (tid & 7) * 8;

    float acc[4][4] = {{0.f}};

    for (int k0 = 0; k0 < K; k0 += BK) {
        const float4* a4 = (const float4*)(A + aphys + k0 + acol);
        float4 av0 = a4[0], av1 = a4[1];
        const float4* b4 = (const float4*)(W + (size_t)(k0 + brow) * N + bn + bcol);
        float4 bv0 = b4[0], bv1 = b4[1];
        As[arow][acol + 0] = av0.x; As[arow][acol + 1] = av0.y;
        As[arow][acol + 2] = av0.z; As[arow][acol + 3] = av0.w;
        As[arow][acol + 4] = av1.x; As[arow][acol + 5] = av1.y;
        As[arow][acol + 6] = av1.z; As[arow][acol + 7] = av1.w;
        Bs[brow][bcol + 0] = bv0.x; Bs[brow][bcol + 1] = bv0.y;
        Bs[brow][bcol + 2] = bv0.z; Bs[brow][bcol + 3] = bv0.w;
        Bs[brow][bcol + 4] = bv1.x; Bs[brow][bcol + 5] = bv1.y;
        Bs[brow][bcol + 6] = bv1.z; Bs[brow][bcol + 7] = bv1.w;
        __syncthreads();
        #pragma unroll
        for (int kk = 0; kk < BK; ++kk) {
            float a0 = As[ty*4+0][kk], a1 = As[ty*4+1][kk];
            float a2 = As[ty*4+2][kk], a3 = As[ty*4+3][kk];
            float b0 = Bs[kk][tx*4+0], b1 = Bs[kk][tx*4+1];
            float b2 = Bs[kk][tx*4+2], b3 = Bs[kk][tx*4+3];
            acc[0][0] += a0*b0; acc[0][1] += a0*b1; acc[0][2] += a0*b2; acc[0][3] += a0*b3;
            acc[1][0] += a1*b0; acc[1][1] += a1*b1; acc[1][2] += a1*b2; acc[1][3] += a1*b3;
            acc[2][0] += a2*b0; acc[2][1] += a2*b1; acc[2][2] += a2*b2; acc[2][3] += a2*b3;
            acc[3][0] += a3*b0; acc[3][1] += a3*b1; acc[3][2] += a3*b2; acc[3][3] += a3*b3;
        }
        __syncthreads();
    }

    float bsv[4];
    #pragma unroll
    for (int j = 0; j < 4; ++j) bsv[j] = bias[bn + tx*4 + j];
    #pragma unroll
    for (int i = 0; i < 4; ++i) {
        int r2 = bm + ty*4 + i;
        size_t crow = (size_t)((r2 / S) * cStr + cOff + (r2 % S));
        float* cp = C + crow * (size_t)N + bn + tx*4;
        #pragma unroll
        for (int j = 0; j < 4; ++j) cp[j] = acc[i][j] + bsv[j];
    }
}

// ---------------------------------------------------------------------------
// RMS norm + scale + RoPE; emits bf16 Q/K/V all row-major [b,h,n,d].
// ---------------------------------------------------------------------------
__global__ __launch_bounds__(256) void rms_rope_pack(
    const float* __restrict__ QKV,
    const float* __restrict__ qs_in, const float* __restrict__ ks_in,
    const float* __restrict__ qs_ctx, const float* __restrict__ ks_ctx,
    bf16* __restrict__ Q, bf16* __restrict__ K, bf16* __restrict__ V)
{
    __shared__ float qrow[DIMC];
    __shared__ float krow[DIMC];
    __shared__ float rq[4], rk[4];

    int token = blockIdx.x;
    int b = token / NTOK;
    int p = token % NTOK;
    bool is_ctx = (p < SCTX);
    const float* qs = is_ctx ? qs_ctx : qs_in;
    const float* ks = is_ctx ? ks_ctx : ks_in;

    int t = threadIdx.x;
    const float* row = QKV + (size_t)token * NQKV;

    float ssq_q = 0.f, ssq_k = 0.f;
    #pragma unroll
    for (int i = 0; i < 6; ++i) {
        int c = t + 256 * i;
        float q = row[c];
        float k = row[DIMC + c];
        qrow[c] = q; krow[c] = k;
        ssq_q += q * q; ssq_k += k * k;
    }
    for (int o = 32; o > 0; o >>= 1) {
        ssq_q += __shfl_down(ssq_q, o);
        ssq_k += __shfl_down(ssq_k, o);
    }
    if ((t & 63) == 0) { rq[t >> 6] = ssq_q; rk[t >> 6] = ssq_k; }
    __syncthreads();
    float sq = rq[0] + rq[1] + rq[2] + rq[3];
    float sk = rk[0] + rk[1] + rk[2] + rk[3];
    float invq = rsqrtf(sq * (1.0f / DIMC) + 1e-6f);
    float invk = rsqrtf(sk * (1.0f / DIMC) + 1e-6f);

    #pragma unroll
    for (int i = 0; i < 6; ++i) {
        int c = t + 256 * i;
        int h = c >> 7, d = c & 127;
        int j = d & 63;
        float inv_freq = powf(10000.0f, -(float)j * (1.0f / 64.0f));
        float ang = (float)p * inv_freq;
        float sn, cs;
        sincosf(ang, &sn, &cs);
        int pc = (d < 64) ? (c + 64) : (c - 64);

        float self_q = qrow[c]  * invq * qs[c];
        float part_q = qrow[pc] * invq * qs[pc];
        float qo = (d < 64) ? (self_q * cs - part_q * sn)
                            : (self_q * cs + part_q * sn);

        float self_k = krow[c]  * invk * ks[c];
        float part_k = krow[pc] * invk * ks[pc];
        float ko = (d < 64) ? (self_k * cs - part_k * sn)
                            : (self_k * cs + part_k * sn);

        float v = row[2 * DIMC + c];

        size_t qi = ((size_t)(b * NH + h) * NTOK + p) * HD + d;
        Q[qi] = (bf16)qo;
        K[qi] = (bf16)ko;
        V[qi] = (bf16)v;
    }
}

// ---------------------------------------------------------------------------
// Flash attention, bf16 MFMA (16x16x32), fp32 accumulate, online softmax.
// Block = 256 thr (4 waves), 64 queries/block, key tiles of 64.
// ---------------------------------------------------------------------------
__global__ __launch_bounds__(256) void attn_mfma(
    const unsigned short* __restrict__ Qh,
    const unsigned short* __restrict__ Kh,
    const unsigned short* __restrict__ Vh,
    float* __restrict__ O)
{
    __shared__ unsigned short k_lds[64][136];       // +8 pad: bank-friendly b128 reads
    __shared__ unsigned short v_lds[16][64][8];     // B-frag-packed: [kt*8+nt][lane][jj]
    __shared__ unsigned short p_lds[4][2][512];     // per-wave P in A-frag order

    int tid = threadIdx.x;
    int wv = tid >> 6, lane = tid & 63;
    int quad = lane >> 4, l16 = lane & 15;

    int qt = blockIdx.x % (NTOK / 64);
    int bh = blockIdx.x / (NTOK / 64);
    int b = bh / NH, h = bh % NH;
    int p0 = qt * 64 + wv * 16;

    size_t base = (size_t)bh * NTOK * HD;

    // Q A-frags: A[m=l16][k=quad*8+j], dk-tile of 32 per frag
    short8 qf[4];
    {
        const unsigned short* qrow = Qh + base + (size_t)(p0 + l16) * HD + quad * 8;
        #pragma unroll
        for (int dk = 0; dk < 4; ++dk)
            qf[dk] = *(const short8*)(qrow + dk * 32);
    }

    float m_r[4], l_r[4];
    f32x4 o_acc[8];
    #pragma unroll
    for (int r = 0; r < 4; ++r) { m_r[r] = -1e30f; l_r[r] = 0.f; }
    #pragma unroll
    for (int nt = 0; nt < 8; ++nt) o_acc[nt] = (f32x4){0.f, 0.f, 0.f, 0.f};

    const float cscale = 0.08838834764831845f * 1.44269504088896f; // 1/sqrt(128)*log2(e)

    // staging decomposition
    int jr = tid >> 2;                 // row 0..63
    int c0 = (tid & 3) * 8;            // col chunk
    int kt_s = jr >> 5;
    int jrel = jr & 31;
    int lb_s = (jrel >> 3) << 4;
    int jj_s = jrel & 7;

    for (int j0 = 0; j0 < NTOK; j0 += 64) {
        // ---- stage K (row-major) and V (B-frag-packed) ----
        const unsigned short* krow = Kh + base + (size_t)(j0 + jr) * HD;
        const unsigned short* vrow = Vh + base + (size_t)(j0 + jr) * HD;
        #pragma unroll
        for (int it = 0; it < 4; ++it) {
            int d0 = c0 + it * 32;
            short8 kv = *(const short8*)(krow + d0);
            *(short8*)&k_lds[jr][d0] = kv;
            short8 vv = *(const short8*)(vrow + d0);
            const unsigned short* vp = (const unsigned short*)&vv;
            #pragma unroll
            for (int i = 0; i < 8; ++i) {
                int d = d0 + i;
                v_lds[kt_s * 8 + (d >> 4)][lb_s + (d & 15)][jj_s] = vp[i];
            }
        }
        __syncthreads();

        // ---- S = Q K^T : 4 key-subtiles x 4 dk MFMAs ----
        f32x4 s[4];
        #pragma unroll
        for (int n = 0; n < 4; ++n) {
            f32x4 acc = (f32x4){0.f, 0.f, 0.f, 0.f};
            #pragma unroll
            for (int dk = 0; dk < 4; ++dk) {
                short8 kf = *(const short8*)&k_lds[n * 16 + l16][dk * 32 + quad * 8];
                acc = __builtin_amdgcn_mfma_f32_16x16x32_bf16(qf[dk], kf, acc, 0, 0, 0);
            }
            s[n] = acc;
        }

        // ---- online softmax (rows = quad*4+r, quad-local reductions) ----
        float mnew[4], alpha[4], rs[4];
        #pragma unroll
        for (int r = 0; r < 4; ++r) {
            float t = fmaxf(fmaxf(s[0][r], s[1][r]), fmaxf(s[2][r], s[3][r]));
            t = fmaxf(t, __shfl_xor(t, 1));
            t = fmaxf(t, __shfl_xor(t, 2));
            t = fmaxf(t, __shfl_xor(t, 4));
            t = fmaxf(t, __shfl_xor(t, 8));
            mnew[r] = fmaxf(m_r[r], t * cscale);
            alpha[r] = exp2f(m_r[r] - mnew[r]);
            m_r[r] = mnew[r];
            rs[r] = 0.f;
        }

        // P = exp2(S*cscale - m), write to per-wave LDS in A-frag order
        #pragma unroll
        for (int n = 0; n < 4; ++n) {
            int k = n * 16 + l16;
            int ktile = k >> 5, jj = k & 7;
            int lbase = ((k >> 3) & 3) * 16 + quad * 4;
            #pragma unroll
            for (int r = 0; r < 4; ++r) {
                float e = exp2f(s[n][r] * cscale - mnew[r]);
                rs[r] += e;
                bf16 eb = (bf16)e;
                p_lds[wv][ktile][(lbase + r) * 8 + jj] = *(unsigned short*)&eb;
            }
        }
        #pragma unroll
        for (int r = 0; r < 4; ++r) {
            float t = rs[r];
            t += __shfl_xor(t, 1);
            t += __shfl_xor(t, 2);
            t += __shfl_xor(t, 4);
            t += __shfl_xor(t, 8);
            l_r[r] = l_r[r] * alpha[r] + t;
        }
        #pragma unroll
        for (int nt = 0; nt < 8; ++nt) {
            #pragma unroll
            for (int r = 0; r < 4; ++r) o_acc[nt][r] *= alpha[r];
        }

        // ---- O += P V ----
        #pragma unroll
        for (int ktile = 0; ktile < 2; ++ktile) {
            short8 pf = *(const short8*)&p_lds[wv][ktile][lane * 8];
            #pragma unroll
            for (int nt = 0; nt < 8; ++nt) {
                short8 vf = *(const short8*)&v_lds[ktile * 8 + nt][lane][0];
                o_acc[nt] = __builtin_amdgcn_mfma_f32_16x16x32_bf16(pf, vf, o_acc[nt], 0, 0, 0);
            }
        }
        __syncthreads();
    }

    // ---- epilogue: normalize and store fp32 ----
    float invl[4];
    #pragma unroll
    for (int r = 0; r < 4; ++r) invl[r] = 1.0f / l_r[r];
    #pragma unroll
    for (int nt = 0; nt < 8; ++nt) {
        #pragma unroll
        for (int r = 0; r < 4; ++r) {
            int p = p0 + quad * 4 + r;
            O[((size_t)(b * NTOK) + p) * DIMC + h * HD + nt * 16 + l16] =
                o_acc[nt][r] * invl[r];
        }
    }
}

// ---------------------------------------------------------------------------
extern "C" void kernel_launch(void* const* d_in, const int* in_sizes, int n_in,
                              void* d_out, int out_size, void* d_ws, size_t ws_size,
                              hipStream_t stream)
{
    const float* input     = (const float*)d_in[0];
    const float* context   = (const float*)d_in[1];
    const float* W_qkv_in  = (const float*)d_in[2];
    const float* b_qkv_in  = (const float*)d_in[3];
    const float* W_qkv_ctx = (const float*)d_in[4];
    const float* b_qkv_ctx = (const float*)d_in[5];
    const float* qs_in     = (const float*)d_in[6];
    const float* ks_in     = (const float*)d_in[7];
    const float* qs_ctx    = (const float*)d_in[8];
    const float* ks_ctx    = (const float*)d_in[9];
    const float* W_out_in  = (const float*)d_in[10];
    const float* b_out_in  = (const float*)d_in[11];
    const float* W_out_ctx = (const float*)d_in[12];
    const float* b_out_ctx = (const float*)d_in[13];
    float* out = (float*)d_out;

    char* ws = (char*)d_ws;
    float* QKV = (float*)ws;                          // [2*2304, 4608] fp32 (84.9 MB)
    float* O   = (float*)ws;                          // overlaps QKV (dead by then)
    size_t off = (size_t)BATCH * NTOK * NQKV * sizeof(float);
    bf16* Qb = (bf16*)(ws + off);                     // [2,12,2304,128] bf16
    bf16* Kb = Qb + (size_t)BATCH * NH * NTOK * HD;
    bf16* Vb = Kb + (size_t)BATCH * NH * NTOK * HD;

    dim3 blk(256);

    gemm_bias<<<dim3(NQKV / BN, (BATCH * SIN) / BM), blk, 0, stream>>>(
        input, W_qkv_in, b_qkv_in, QKV,
        BATCH * SIN, NQKV, DIMC, SIN, SIN, 0, NTOK, SCTX);
    gemm_bias<<<dim3(NQKV / BN, (BATCH * SCTX) / BM), blk, 0, stream>>>(
        context, W_qkv_ctx, b_qkv_ctx, QKV,
        BATCH * SCTX, NQKV, DIMC, SCTX, SCTX, 0, NTOK, 0);

    rms_rope_pack<<<BATCH * NTOK, 256, 0, stream>>>(
        QKV, qs_in, ks_in, qs_ctx, ks_ctx, Qb, Kb, Vb);

    attn_mfma<<<BATCH * NH * (NTOK / 64), 256, 0, stream>>>(
        (const unsigned short*)Qb, (const unsigned short*)Kb,
        (const unsigned short*)Vb, O);

    gemm_bias<<<dim3(DIMC / BN, (BATCH * SIN) / BM), blk, 0, stream>>>(
        O, W_out_in, b_out_in, out,
        BATCH * SIN, DIMC, DIMC, SIN, NTOK, SCTX, SIN, 0);
    gemm_bias<<<dim3(DIMC / BN, (BATCH * SCTX) / BM), blk, 0, stream>>>(
        O, W_out_ctx, b_out_ctx, out + (size_t)BATCH * SIN * DIMC,
        BATCH * SCTX, DIMC, DIMC, SCTX, NTOK, 0, SCTX, 0);
}

// Round 4
// 682.213 us; speedup vs baseline: 6.2215x; 2.3747x over previous
//
#include <hip/hip_runtime.h>
#include <hip/hip_bf16.h>

typedef __hip_bfloat16 bf16;
typedef __attribute__((ext_vector_type(8))) short short8;
typedef __attribute__((ext_vector_type(4))) float f32x4;

#define DIMC 1536
#define NQKV 4608
#define NH   12
#define HD   128
#define NTOK 2304
#define SCTX 256
#define SIN  2048
#define BATCH 2

__device__ __forceinline__ float bf2f(unsigned short u) {
    return __uint_as_float(((unsigned int)u) << 16);
}
__device__ __forceinline__ unsigned short f2bfu(float f) {
    bf16 h = (bf16)f; return *(unsigned short*)&h;
}

// async global->LDS, 16B per lane; LDS dest = wave-uniform base + lane*16
#define GLOAD16(gp, lp) __builtin_amdgcn_global_load_lds(                      \
    (__attribute__((address_space(1))) void*)(gp),                             \
    (__attribute__((address_space(3))) void*)(lp), 16, 0, 0)

// ---------------------------------------------------------------------------
// fp32 -> bf16 elementwise (4 elems/thread)
// ---------------------------------------------------------------------------
__global__ __launch_bounds__(256) void cvt_bf16(
    const float* __restrict__ X, unsigned short* __restrict__ Y, int n4)
{
    int i = blockIdx.x * 256 + threadIdx.x;
    if (i < n4) {
        float4 v = ((const float4*)X)[i];
        union { unsigned short u[4]; uint2 p; } o;
        o.u[0] = f2bfu(v.x); o.u[1] = f2bfu(v.y);
        o.u[2] = f2bfu(v.z); o.u[3] = f2bfu(v.w);
        ((uint2*)Y)[i] = o.p;
    }
}

// ---------------------------------------------------------------------------
// W[K][N] fp32 -> Wt[N][K] bf16 (32x32 LDS tile transpose)
// ---------------------------------------------------------------------------
__global__ __launch_bounds__(256) void transpose_cvt(
    const float* __restrict__ W, unsigned short* __restrict__ Wt, int K, int N)
{
    __shared__ float tile[32][33];
    int n0 = blockIdx.x * 32, k0 = blockIdx.y * 32;
    int tx = threadIdx.x & 31, ty = threadIdx.x >> 5;   // ty 0..7
    #pragma unroll
    for (int i = 0; i < 4; ++i) {
        int kk = ty + i * 8;
        tile[kk][tx] = W[(size_t)(k0 + kk) * N + n0 + tx];
    }
    __syncthreads();
    #pragma unroll
    for (int i = 0; i < 4; ++i) {
        int nn = ty + i * 8;
        Wt[(size_t)(n0 + nn) * K + k0 + tx] = f2bfu(tile[tx][nn]);
    }
}

// ---------------------------------------------------------------------------
// bf16 MFMA GEMM (m97 structure): C[cmap(r)][n] = sum_k A[amap(r)][k]*Wt[n][k] + bias[n]
// 128x128 tile, BK=32, 4 waves (2x2), global_load_lds staging, XOR-swizzled LDS.
// CT = float (fp32 C) or unsigned short (bf16 C). C pitch = N.
// ---------------------------------------------------------------------------
__device__ __forceinline__ void storeC(float* p, float v) { *p = v; }
__device__ __forceinline__ void storeC(unsigned short* p, float v) { *p = f2bfu(v); }

template <typename CT>
__global__ __launch_bounds__(256) void gemm_mfma(
    const unsigned short* __restrict__ A, const unsigned short* __restrict__ Wt,
    const float* __restrict__ bias, CT* __restrict__ C,
    int N, int K, int S, int aStr, int aOff, int cStr, int cOff)
{
    __shared__ __align__(16) unsigned short a_lds[128 * 32];
    __shared__ __align__(16) unsigned short b_lds[128 * 32];

    int tid = threadIdx.x;
    int wv = tid >> 6, lane = tid & 63;
    int wm = wv >> 1, wn = wv & 1;
    int quad = lane >> 4, l16 = lane & 15;
    int bm = blockIdx.y * 128, bn = blockIdx.x * 128;

    // staging: granule gi in [0,512): row m = gi>>2, LDS chunk c' = gi&3 holds
    // global chunk c = c' ^ ((m>>1)&3). Rounds 0/1 are rows 0..63 / 64..127.
    int m0 = tid >> 2;
    int c  = (tid & 3) ^ ((m0 >> 1) & 3);
    int r0 = bm + m0, r1 = bm + m0 + 64;
    size_t apA0 = ((size_t)((r0 / S) * aStr + aOff + (r0 % S))) * (size_t)K + c * 8;
    size_t apA1 = ((size_t)((r1 / S) * aStr + aOff + (r1 % S))) * (size_t)K + c * 8;
    size_t apB0 = (size_t)(bn + m0) * K + c * 8;
    size_t apB1 = (size_t)(bn + m0 + 64) * K + c * 8;

    unsigned short* ldsA0 = &a_lds[(wv * 64) * 8];
    unsigned short* ldsA1 = &a_lds[(256 + wv * 64) * 8];
    unsigned short* ldsB0 = &b_lds[(wv * 64) * 8];
    unsigned short* ldsB1 = &b_lds[(256 + wv * 64) * 8];

    // frag read offsets (elements)
    int gA[4], gB[4];
    #pragma unroll
    for (int mt = 0; mt < 4; ++mt) {
        int m = wm * 64 + mt * 16 + l16;
        gA[mt] = (m * 4 + (quad ^ ((m >> 1) & 3))) * 8;
    }
    #pragma unroll
    for (int nt = 0; nt < 4; ++nt) {
        int n = wn * 64 + nt * 16 + l16;
        gB[nt] = (n * 4 + (quad ^ ((n >> 1) & 3))) * 8;
    }

    f32x4 acc[4][4];
    #pragma unroll
    for (int mt = 0; mt < 4; ++mt)
        #pragma unroll
        for (int nt = 0; nt < 4; ++nt) acc[mt][nt] = (f32x4){0.f, 0.f, 0.f, 0.f};

    for (int k0 = 0; k0 < K; k0 += 32) {
        GLOAD16(A + apA0 + k0, ldsA0);
        GLOAD16(A + apA1 + k0, ldsA1);
        GLOAD16(Wt + apB0 + k0, ldsB0);
        GLOAD16(Wt + apB1 + k0, ldsB1);
        __syncthreads();

        short8 af[4], bfr[4];
        #pragma unroll
        for (int mt = 0; mt < 4; ++mt) af[mt] = *(const short8*)&a_lds[gA[mt]];
        #pragma unroll
        for (int nt = 0; nt < 4; ++nt) bfr[nt] = *(const short8*)&b_lds[gB[nt]];
        #pragma unroll
        for (int mt = 0; mt < 4; ++mt)
            #pragma unroll
            for (int nt = 0; nt < 4; ++nt)
                acc[mt][nt] = __builtin_amdgcn_mfma_f32_16x16x32_bf16(
                    af[mt], bfr[nt], acc[mt][nt], 0, 0, 0);
        __syncthreads();
    }

    float bv[4];
    #pragma unroll
    for (int nt = 0; nt < 4; ++nt) bv[nt] = bias[bn + wn * 64 + nt * 16 + l16];
    #pragma unroll
    for (int mt = 0; mt < 4; ++mt) {
        #pragma unroll
        for (int r = 0; r < 4; ++r) {
            int row = bm + wm * 64 + mt * 16 + quad * 4 + r;
            size_t crow = (size_t)((row / S) * cStr + cOff + (row % S));
            CT* cp = C + crow * (size_t)N + bn + wn * 64 + l16;
            #pragma unroll
            for (int nt = 0; nt < 4; ++nt)
                storeC(cp + nt * 16, acc[mt][nt][r] + bv[nt]);
        }
    }
}

// ---------------------------------------------------------------------------
// RMS norm + scale + RoPE; QKV in bf16, emits bf16 Q/K/V row-major [b,h,n,d].
// ---------------------------------------------------------------------------
__global__ __launch_bounds__(256) void rms_rope_pack(
    const unsigned short* __restrict__ QKV,
    const float* __restrict__ qs_in, const float* __restrict__ ks_in,
    const float* __restrict__ qs_ctx, const float* __restrict__ ks_ctx,
    bf16* __restrict__ Q, bf16* __restrict__ K, bf16* __restrict__ V)
{
    __shared__ float qrow[DIMC];
    __shared__ float krow[DIMC];
    __shared__ float rq[4], rk[4];

    int token = blockIdx.x;
    int b = token / NTOK;
    int p = token % NTOK;
    bool is_ctx = (p < SCTX);
    const float* qs = is_ctx ? qs_ctx : qs_in;
    const float* ks = is_ctx ? ks_ctx : ks_in;

    int t = threadIdx.x;
    const unsigned short* row = QKV + (size_t)token * NQKV;

    float ssq_q = 0.f, ssq_k = 0.f;
    #pragma unroll
    for (int i = 0; i < 6; ++i) {
        int c = t + 256 * i;
        float q = bf2f(row[c]);
        float k = bf2f(row[DIMC + c]);
        qrow[c] = q; krow[c] = k;
        ssq_q += q * q; ssq_k += k * k;
    }
    for (int o = 32; o > 0; o >>= 1) {
        ssq_q += __shfl_down(ssq_q, o);
        ssq_k += __shfl_down(ssq_k, o);
    }
    if ((t & 63) == 0) { rq[t >> 6] = ssq_q; rk[t >> 6] = ssq_k; }
    __syncthreads();
    float sq = rq[0] + rq[1] + rq[2] + rq[3];
    float sk = rk[0] + rk[1] + rk[2] + rk[3];
    float invq = rsqrtf(sq * (1.0f / DIMC) + 1e-6f);
    float invk = rsqrtf(sk * (1.0f / DIMC) + 1e-6f);

    #pragma unroll
    for (int i = 0; i < 6; ++i) {
        int c = t + 256 * i;
        int h = c >> 7, d = c & 127;
        int j = d & 63;
        float inv_freq = powf(10000.0f, -(float)j * (1.0f / 64.0f));
        float ang = (float)p * inv_freq;
        float sn, cs;
        sincosf(ang, &sn, &cs);
        int pc = (d < 64) ? (c + 64) : (c - 64);

        float self_q = qrow[c]  * invq * qs[c];
        float part_q = qrow[pc] * invq * qs[pc];
        float qo = (d < 64) ? (self_q * cs - part_q * sn)
                            : (self_q * cs + part_q * sn);

        float self_k = krow[c]  * invk * ks[c];
        float part_k = krow[pc] * invk * ks[pc];
        float ko = (d < 64) ? (self_k * cs - part_k * sn)
                            : (self_k * cs + part_k * sn);

        float v = bf2f(row[2 * DIMC + c]);

        size_t qi = ((size_t)(b * NH + h) * NTOK + p) * HD + d;
        Q[qi] = (bf16)qo;
        K[qi] = (bf16)ko;
        V[qi] = (bf16)v;
    }
}

// ---------------------------------------------------------------------------
// Flash attention, bf16 MFMA, fp32 accumulate, online softmax. O is bf16.
// ---------------------------------------------------------------------------
__global__ __launch_bounds__(256) void attn_mfma(
    const unsigned short* __restrict__ Qh,
    const unsigned short* __restrict__ Kh,
    const unsigned short* __restrict__ Vh,
    bf16* __restrict__ O)
{
    __shared__ unsigned short k_lds[64][136];
    __shared__ unsigned short v_lds[16][64][8];
    __shared__ unsigned short p_lds[4][2][512];

    int tid = threadIdx.x;
    int wv = tid >> 6, lane = tid & 63;
    int quad = lane >> 4, l16 = lane & 15;

    int qt = blockIdx.x % (NTOK / 64);
    int bh = blockIdx.x / (NTOK / 64);
    int b = bh / NH, h = bh % NH;
    int p0 = qt * 64 + wv * 16;

    size_t base = (size_t)bh * NTOK * HD;

    short8 qf[4];
    {
        const unsigned short* qrow = Qh + base + (size_t)(p0 + l16) * HD + quad * 8;
        #pragma unroll
        for (int dk = 0; dk < 4; ++dk)
            qf[dk] = *(const short8*)(qrow + dk * 32);
    }

    float m_r[4], l_r[4];
    f32x4 o_acc[8];
    #pragma unroll
    for (int r = 0; r < 4; ++r) { m_r[r] = -1e30f; l_r[r] = 0.f; }
    #pragma unroll
    for (int nt = 0; nt < 8; ++nt) o_acc[nt] = (f32x4){0.f, 0.f, 0.f, 0.f};

    const float cscale = 0.08838834764831845f * 1.44269504088896f;

    int jr = tid >> 2;
    int c0 = (tid & 3) * 8;
    int kt_s = jr >> 5;
    int jrel = jr & 31;
    int lb_s = (jrel >> 3) << 4;
    int jj_s = jrel & 7;

    for (int j0 = 0; j0 < NTOK; j0 += 64) {
        const unsigned short* krow = Kh + base + (size_t)(j0 + jr) * HD;
        const unsigned short* vrow = Vh + base + (size_t)(j0 + jr) * HD;
        #pragma unroll
        for (int it = 0; it < 4; ++it) {
            int d0 = c0 + it * 32;
            short8 kv = *(const short8*)(krow + d0);
            *(short8*)&k_lds[jr][d0] = kv;
            short8 vv = *(const short8*)(vrow + d0);
            const unsigned short* vp = (const unsigned short*)&vv;
            #pragma unroll
            for (int i = 0; i < 8; ++i) {
                int d = d0 + i;
                v_lds[kt_s * 8 + (d >> 4)][lb_s + (d & 15)][jj_s] = vp[i];
            }
        }
        __syncthreads();

        f32x4 s[4];
        #pragma unroll
        for (int n = 0; n < 4; ++n) {
            f32x4 acc = (f32x4){0.f, 0.f, 0.f, 0.f};
            #pragma unroll
            for (int dk = 0; dk < 4; ++dk) {
                short8 kf = *(const short8*)&k_lds[n * 16 + l16][dk * 32 + quad * 8];
                acc = __builtin_amdgcn_mfma_f32_16x16x32_bf16(qf[dk], kf, acc, 0, 0, 0);
            }
            s[n] = acc;
        }

        float mnew[4], alpha[4], rs[4];
        #pragma unroll
        for (int r = 0; r < 4; ++r) {
            float t = fmaxf(fmaxf(s[0][r], s[1][r]), fmaxf(s[2][r], s[3][r]));
            t = fmaxf(t, __shfl_xor(t, 1));
            t = fmaxf(t, __shfl_xor(t, 2));
            t = fmaxf(t, __shfl_xor(t, 4));
            t = fmaxf(t, __shfl_xor(t, 8));
            mnew[r] = fmaxf(m_r[r], t * cscale);
            alpha[r] = exp2f(m_r[r] - mnew[r]);
            m_r[r] = mnew[r];
            rs[r] = 0.f;
        }

        #pragma unroll
        for (int n = 0; n < 4; ++n) {
            int k = n * 16 + l16;
            int ktile = k >> 5, jj = k & 7;
            int lbase = ((k >> 3) & 3) * 16 + quad * 4;
            #pragma unroll
            for (int r = 0; r < 4; ++r) {
                float e = exp2f(s[n][r] * cscale - mnew[r]);
                rs[r] += e;
                p_lds[wv][ktile][(lbase + r) * 8 + jj] = f2bfu(e);
            }
        }
        #pragma unroll
        for (int r = 0; r < 4; ++r) {
            float t = rs[r];
            t += __shfl_xor(t, 1);
            t += __shfl_xor(t, 2);
            t += __shfl_xor(t, 4);
            t += __shfl_xor(t, 8);
            l_r[r] = l_r[r] * alpha[r] + t;
        }
        #pragma unroll
        for (int nt = 0; nt < 8; ++nt) {
            #pragma unroll
            for (int r = 0; r < 4; ++r) o_acc[nt][r] *= alpha[r];
        }

        #pragma unroll
        for (int ktile = 0; ktile < 2; ++ktile) {
            short8 pf = *(const short8*)&p_lds[wv][ktile][lane * 8];
            #pragma unroll
            for (int nt = 0; nt < 8; ++nt) {
                short8 vf = *(const short8*)&v_lds[ktile * 8 + nt][lane][0];
                o_acc[nt] = __builtin_amdgcn_mfma_f32_16x16x32_bf16(pf, vf, o_acc[nt], 0, 0, 0);
            }
        }
        __syncthreads();
    }

    float invl[4];
    #pragma unroll
    for (int r = 0; r < 4; ++r) invl[r] = 1.0f / l_r[r];
    #pragma unroll
    for (int nt = 0; nt < 8; ++nt) {
        #pragma unroll
        for (int r = 0; r < 4; ++r) {
            int p = p0 + quad * 4 + r;
            O[((size_t)(b * NTOK) + p) * DIMC + h * HD + nt * 16 + l16] =
                (bf16)(o_acc[nt][r] * invl[r]);
        }
    }
}

// ---------------------------------------------------------------------------
extern "C" void kernel_launch(void* const* d_in, const int* in_sizes, int n_in,
                              void* d_out, int out_size, void* d_ws, size_t ws_size,
                              hipStream_t stream)
{
    const float* input     = (const float*)d_in[0];
    const float* context   = (const float*)d_in[1];
    const float* W_qkv_in  = (const float*)d_in[2];
    const float* b_qkv_in  = (const float*)d_in[3];
    const float* W_qkv_ctx = (const float*)d_in[4];
    const float* b_qkv_ctx = (const float*)d_in[5];
    const float* qs_in     = (const float*)d_in[6];
    const float* ks_in     = (const float*)d_in[7];
    const float* qs_ctx    = (const float*)d_in[8];
    const float* ks_ctx    = (const float*)d_in[9];
    const float* W_out_in  = (const float*)d_in[10];
    const float* b_out_in  = (const float*)d_in[11];
    const float* W_out_ctx = (const float*)d_in[12];
    const float* b_out_ctx = (const float*)d_in[13];
    float* out = (float*)d_out;

    // workspace layout (total 127,401,984 B == round-3 footprint, known to fit)
    char* ws = (char*)d_ws;
    unsigned short* QKVb = (unsigned short*)ws;                    // [4608][4608] bf16
    bf16*           Ob   = (bf16*)ws;                              // [4608][1536] bf16 (after QKVb dead)
    unsigned short* Qb   = (unsigned short*)(ws + 42467328);       // [2,12,2304,128]
    unsigned short* Kb   = Qb + (size_t)BATCH * NH * NTOK * HD;
    unsigned short* Vb   = Kb + (size_t)BATCH * NH * NTOK * HD;
    unsigned short* AbIn  = (unsigned short*)(ws + 84934656);      // [4096][1536]
    unsigned short* AbCtx = AbIn + (size_t)BATCH * SIN * DIMC;     // [512][1536]
    unsigned short* WtOutIn  = (unsigned short*)(ws + 84934656);   // overlays Ab (dead by then)
    unsigned short* WtOutCtx = WtOutIn + (size_t)DIMC * DIMC;
    unsigned short* WtQkvIn  = (unsigned short*)(ws + 99090432);   // [4608][1536]
    unsigned short* WtQkvCtx = (unsigned short*)(ws + 113246208);  // [4608][1536]

    // --- convert activations + QKV weights ---
    cvt_bf16<<<(BATCH * SIN * DIMC / 4 + 255) / 256, 256, 0, stream>>>(
        input, AbIn, BATCH * SIN * DIMC / 4);
    cvt_bf16<<<(BATCH * SCTX * DIMC / 4 + 255) / 256, 256, 0, stream>>>(
        context, AbCtx, BATCH * SCTX * DIMC / 4);
    transpose_cvt<<<dim3(NQKV / 32, DIMC / 32), 256, 0, stream>>>(W_qkv_in, WtQkvIn, DIMC, NQKV);
    transpose_cvt<<<dim3(NQKV / 32, DIMC / 32), 256, 0, stream>>>(W_qkv_ctx, WtQkvCtx, DIMC, NQKV);

    // --- QKV projections (bf16 C, scatter into combined ctx-first order) ---
    gemm_mfma<unsigned short><<<dim3(NQKV / 128, (BATCH * SIN) / 128), 256, 0, stream>>>(
        AbIn, WtQkvIn, b_qkv_in, QKVb, NQKV, DIMC, SIN, SIN, 0, NTOK, SCTX);
    gemm_mfma<unsigned short><<<dim3(NQKV / 128, (BATCH * SCTX) / 128), 256, 0, stream>>>(
        AbCtx, WtQkvCtx, b_qkv_ctx, QKVb, NQKV, DIMC, SCTX, SCTX, 0, NTOK, 0);

    // --- RMS norm + RoPE + head pack ---
    rms_rope_pack<<<BATCH * NTOK, 256, 0, stream>>>(
        QKVb, qs_in, ks_in, qs_ctx, ks_ctx, (bf16*)Qb, (bf16*)Kb, (bf16*)Vb);

    // --- attention (writes bf16 O over dead QKVb region) ---
    attn_mfma<<<BATCH * NH * (NTOK / 64), 256, 0, stream>>>(Qb, Kb, Vb, Ob);

    // --- out-proj weights (into dead Ab region), then projections (fp32 C) ---
    transpose_cvt<<<dim3(DIMC / 32, DIMC / 32), 256, 0, stream>>>(W_out_in, WtOutIn, DIMC, DIMC);
    transpose_cvt<<<dim3(DIMC / 32, DIMC / 32), 256, 0, stream>>>(W_out_ctx, WtOutCtx, DIMC, DIMC);

    gemm_mfma<float><<<dim3(DIMC / 128, (BATCH * SIN) / 128), 256, 0, stream>>>(
        (const unsigned short*)Ob, WtOutIn, b_out_in, out,
        DIMC, DIMC, SIN, NTOK, SCTX, SIN, 0);
    gemm_mfma<float><<<dim3(DIMC / 128, (BATCH * SCTX) / 128), 256, 0, stream>>>(
        (const unsigned short*)Ob, WtOutCtx, b_out_ctx, out + (size_t)BATCH * SIN * DIMC,
        DIMC, DIMC, SCTX, NTOK, 0, SCTX, 0);
}

// Round 5
// 555.899 us; speedup vs baseline: 7.6352x; 1.2272x over previous
//
#include <hip/hip_runtime.h>
#include <hip/hip_bf16.h>

typedef __hip_bfloat16 bf16;
typedef __attribute__((ext_vector_type(8))) short short8;
typedef __attribute__((ext_vector_type(4))) float f32x4;

#define DIMC 1536
#define NQKV 4608
#define NH   12
#define HD   128
#define NTOK 2304
#define SCTX 256
#define SIN  2048
#define BATCH 2

__device__ __forceinline__ float bf2f(unsigned short u) {
    return __uint_as_float(((unsigned int)u) << 16);
}
__device__ __forceinline__ unsigned short f2bfu(float f) {
    bf16 h = (bf16)f; return *(unsigned short*)&h;
}

// async global->LDS, 16B per lane; LDS dest = wave-uniform base + lane*16
#define GLOAD16(gp, lp) __builtin_amdgcn_global_load_lds(                      \
    (__attribute__((address_space(1))) void*)(gp),                             \
    (__attribute__((address_space(3))) void*)(lp), 16, 0, 0)

// ---------------------------------------------------------------------------
// fp32 -> bf16 elementwise (4 elems/thread)
// ---------------------------------------------------------------------------
__global__ __launch_bounds__(256) void cvt_bf16(
    const float* __restrict__ X, unsigned short* __restrict__ Y, int n4)
{
    int i = blockIdx.x * 256 + threadIdx.x;
    if (i < n4) {
        float4 v = ((const float4*)X)[i];
        union { unsigned short u[4]; uint2 p; } o;
        o.u[0] = f2bfu(v.x); o.u[1] = f2bfu(v.y);
        o.u[2] = f2bfu(v.z); o.u[3] = f2bfu(v.w);
        ((uint2*)Y)[i] = o.p;
    }
}

// ---------------------------------------------------------------------------
// W[K][N] fp32 -> Wt[N][K] bf16 (32x32 LDS tile transpose)
// ---------------------------------------------------------------------------
__global__ __launch_bounds__(256) void transpose_cvt(
    const float* __restrict__ W, unsigned short* __restrict__ Wt, int K, int N)
{
    __shared__ float tile[32][33];
    int n0 = blockIdx.x * 32, k0 = blockIdx.y * 32;
    int tx = threadIdx.x & 31, ty = threadIdx.x >> 5;
    #pragma unroll
    for (int i = 0; i < 4; ++i) {
        int kk = ty + i * 8;
        tile[kk][tx] = W[(size_t)(k0 + kk) * N + n0 + tx];
    }
    __syncthreads();
    #pragma unroll
    for (int i = 0; i < 4; ++i) {
        int nn = ty + i * 8;
        Wt[(size_t)(n0 + nn) * K + k0 + tx] = f2bfu(tile[tx][nn]);
    }
}

// ---------------------------------------------------------------------------
// bf16 MFMA GEMM (m97 structure), unchanged from round 3.
// ---------------------------------------------------------------------------
__device__ __forceinline__ void storeC(float* p, float v) { *p = v; }
__device__ __forceinline__ void storeC(unsigned short* p, float v) { *p = f2bfu(v); }

template <typename CT>
__global__ __launch_bounds__(256) void gemm_mfma(
    const unsigned short* __restrict__ A, const unsigned short* __restrict__ Wt,
    const float* __restrict__ bias, CT* __restrict__ C,
    int N, int K, int S, int aStr, int aOff, int cStr, int cOff)
{
    __shared__ __align__(16) unsigned short a_lds[128 * 32];
    __shared__ __align__(16) unsigned short b_lds[128 * 32];

    int tid = threadIdx.x;
    int wv = tid >> 6, lane = tid & 63;
    int wm = wv >> 1, wn = wv & 1;
    int quad = lane >> 4, l16 = lane & 15;
    int bm = blockIdx.y * 128, bn = blockIdx.x * 128;

    int m0 = tid >> 2;
    int c  = (tid & 3) ^ ((m0 >> 1) & 3);
    int r0 = bm + m0, r1 = bm + m0 + 64;
    size_t apA0 = ((size_t)((r0 / S) * aStr + aOff + (r0 % S))) * (size_t)K + c * 8;
    size_t apA1 = ((size_t)((r1 / S) * aStr + aOff + (r1 % S))) * (size_t)K + c * 8;
    size_t apB0 = (size_t)(bn + m0) * K + c * 8;
    size_t apB1 = (size_t)(bn + m0 + 64) * K + c * 8;

    unsigned short* ldsA0 = &a_lds[(wv * 64) * 8];
    unsigned short* ldsA1 = &a_lds[(256 + wv * 64) * 8];
    unsigned short* ldsB0 = &b_lds[(wv * 64) * 8];
    unsigned short* ldsB1 = &b_lds[(256 + wv * 64) * 8];

    int gA[4], gB[4];
    #pragma unroll
    for (int mt = 0; mt < 4; ++mt) {
        int m = wm * 64 + mt * 16 + l16;
        gA[mt] = (m * 4 + (quad ^ ((m >> 1) & 3))) * 8;
    }
    #pragma unroll
    for (int nt = 0; nt < 4; ++nt) {
        int n = wn * 64 + nt * 16 + l16;
        gB[nt] = (n * 4 + (quad ^ ((n >> 1) & 3))) * 8;
    }

    f32x4 acc[4][4];
    #pragma unroll
    for (int mt = 0; mt < 4; ++mt)
        #pragma unroll
        for (int nt = 0; nt < 4; ++nt) acc[mt][nt] = (f32x4){0.f, 0.f, 0.f, 0.f};

    for (int k0 = 0; k0 < K; k0 += 32) {
        GLOAD16(A + apA0 + k0, ldsA0);
        GLOAD16(A + apA1 + k0, ldsA1);
        GLOAD16(Wt + apB0 + k0, ldsB0);
        GLOAD16(Wt + apB1 + k0, ldsB1);
        __syncthreads();

        short8 af[4], bfr[4];
        #pragma unroll
        for (int mt = 0; mt < 4; ++mt) af[mt] = *(const short8*)&a_lds[gA[mt]];
        #pragma unroll
        for (int nt = 0; nt < 4; ++nt) bfr[nt] = *(const short8*)&b_lds[gB[nt]];
        #pragma unroll
        for (int mt = 0; mt < 4; ++mt)
            #pragma unroll
            for (int nt = 0; nt < 4; ++nt)
                acc[mt][nt] = __builtin_amdgcn_mfma_f32_16x16x32_bf16(
                    af[mt], bfr[nt], acc[mt][nt], 0, 0, 0);
        __syncthreads();
    }

    float bv[4];
    #pragma unroll
    for (int nt = 0; nt < 4; ++nt) bv[nt] = bias[bn + wn * 64 + nt * 16 + l16];
    #pragma unroll
    for (int mt = 0; mt < 4; ++mt) {
        #pragma unroll
        for (int r = 0; r < 4; ++r) {
            int row = bm + wm * 64 + mt * 16 + quad * 4 + r;
            size_t crow = (size_t)((row / S) * cStr + cOff + (row % S));
            CT* cp = C + crow * (size_t)N + bn + wn * 64 + l16;
            #pragma unroll
            for (int nt = 0; nt < 4; ++nt)
                storeC(cp + nt * 16, acc[mt][nt][r] + bv[nt]);
        }
    }
}

// ---------------------------------------------------------------------------
// RMS norm + scale + RoPE; QKV bf16 in, emits bf16 Q/K row-major [b,h,n,d].
// (V handled by vt_pack.)
// ---------------------------------------------------------------------------
__global__ __launch_bounds__(256) void rms_rope_pack(
    const unsigned short* __restrict__ QKV,
    const float* __restrict__ qs_in, const float* __restrict__ ks_in,
    const float* __restrict__ qs_ctx, const float* __restrict__ ks_ctx,
    bf16* __restrict__ Q, bf16* __restrict__ K)
{
    __shared__ float qrow[DIMC];
    __shared__ float krow[DIMC];
    __shared__ float rq[4], rk[4];

    int token = blockIdx.x;
    int b = token / NTOK;
    int p = token % NTOK;
    bool is_ctx = (p < SCTX);
    const float* qs = is_ctx ? qs_ctx : qs_in;
    const float* ks = is_ctx ? ks_ctx : ks_in;

    int t = threadIdx.x;
    const unsigned short* row = QKV + (size_t)token * NQKV;

    float ssq_q = 0.f, ssq_k = 0.f;
    #pragma unroll
    for (int i = 0; i < 6; ++i) {
        int c = t + 256 * i;
        float q = bf2f(row[c]);
        float k = bf2f(row[DIMC + c]);
        qrow[c] = q; krow[c] = k;
        ssq_q += q * q; ssq_k += k * k;
    }
    for (int o = 32; o > 0; o >>= 1) {
        ssq_q += __shfl_down(ssq_q, o);
        ssq_k += __shfl_down(ssq_k, o);
    }
    if ((t & 63) == 0) { rq[t >> 6] = ssq_q; rk[t >> 6] = ssq_k; }
    __syncthreads();
    float sq = rq[0] + rq[1] + rq[2] + rq[3];
    float sk = rk[0] + rk[1] + rk[2] + rk[3];
    float invq = rsqrtf(sq * (1.0f / DIMC) + 1e-6f);
    float invk = rsqrtf(sk * (1.0f / DIMC) + 1e-6f);

    #pragma unroll
    for (int i = 0; i < 6; ++i) {
        int c = t + 256 * i;
        int h = c >> 7, d = c & 127;
        int j = d & 63;
        float inv_freq = powf(10000.0f, -(float)j * (1.0f / 64.0f));
        float ang = (float)p * inv_freq;
        float sn, cs;
        sincosf(ang, &sn, &cs);
        int pc = (d < 64) ? (c + 64) : (c - 64);

        float self_q = qrow[c]  * invq * qs[c];
        float part_q = qrow[pc] * invq * qs[pc];
        float qo = (d < 64) ? (self_q * cs - part_q * sn)
                            : (self_q * cs + part_q * sn);

        float self_k = krow[c]  * invk * ks[c];
        float part_k = krow[pc] * invk * ks[pc];
        float ko = (d < 64) ? (self_k * cs - part_k * sn)
                            : (self_k * cs + part_k * sn);

        size_t qi = ((size_t)(b * NH + h) * NTOK + p) * HD + d;
        Q[qi] = (bf16)qo;
        K[qi] = (bf16)ko;
    }
}

// ---------------------------------------------------------------------------
// V transpose: QKV[token][2*DIMC + h*HD + d] -> Vt[bh][d][p]  (bf16)
// Block = (bh, 64-token tile).
// ---------------------------------------------------------------------------
__global__ __launch_bounds__(256) void vt_pack(
    const unsigned short* __restrict__ QKV, unsigned short* __restrict__ Vt)
{
    __shared__ unsigned short tileT[128][72];   // [d][p], pad 72 keeps b128 align

    int pt = blockIdx.x % (NTOK / 64);
    int bh = blockIdx.x / (NTOK / 64);
    int b = bh / NH, h = bh % NH;
    int p0 = pt * 64;

    int t = threadIdx.x, wv = t >> 6, l = t & 63;

    // phase A: wave wv loads chunk c = it*4+wv of row p=l; write row-contiguous
    const unsigned short* src =
        QKV + (size_t)(b * NTOK + p0 + l) * NQKV + 2 * DIMC + h * HD;
    #pragma unroll
    for (int it = 0; it < 4; ++it) {
        int c = it * 4 + wv;
        short8 v = *(const short8*)(src + c * 8);
        const unsigned short* vp = (const unsigned short*)&v;
        #pragma unroll
        for (int i = 0; i < 8; ++i) tileT[c * 8 + i][l] = vp[i];
    }
    __syncthreads();

    // phase B: thread owns (d = t>>1, half = t&1): 4 b128 reads + 4 b128 stores
    int d = t >> 1, jh = (t & 1) * 32;
    unsigned short* dst = Vt + ((size_t)bh * HD + d) * NTOK + p0 + jh;
    #pragma unroll
    for (int k = 0; k < 4; ++k) {
        short8 v = *(const short8*)&tileT[d][jh + k * 8];
        *(short8*)(dst + k * 8) = v;
    }
}

// ---------------------------------------------------------------------------
// Flash attention v2: 128 queries/block (4 waves x 32q), key tile 64.
// Q,K row-major [bh][p][d]; V pre-transposed Vt [bh][d][p]. O^T PV formulation.
// global_load_lds staging with XOR chunk swizzle; all frag reads ds_read_b128.
// ---------------------------------------------------------------------------
__global__ __launch_bounds__(256, 2) void attn_mfma(
    const unsigned short* __restrict__ Qh,
    const unsigned short* __restrict__ Kh,
    const unsigned short* __restrict__ Vth,
    bf16* __restrict__ O)
{
    __shared__ __align__(16) unsigned short k_lds[64 * 128];   // [j][d] swizzled
    __shared__ __align__(16) unsigned short v_lds[128 * 64];   // [d][j] swizzled
    __shared__ __align__(16) unsigned short p_lds[4][32][72];  // per-wave P[q][j]
    __shared__ float bc[4][32];

    int tid = threadIdx.x;
    int wv = tid >> 6, lane = tid & 63;
    int quad = lane >> 4, l16 = lane & 15;

    int qt = blockIdx.x % (NTOK / 128);
    int bh = blockIdx.x / (NTOK / 128);
    int b = bh / NH, h = bh % NH;
    int p0 = qt * 128;
    int qw = p0 + wv * 32;                       // this wave's 32 queries

    const unsigned short* Kbh = Kh + (size_t)bh * NTOK * HD;
    const unsigned short* Vbh = Vth + (size_t)bh * HD * NTOK;

    // Q A-frags (2 q-subtiles x 4 dk)
    short8 qf[2][4];
    #pragma unroll
    for (int mt = 0; mt < 2; ++mt) {
        const unsigned short* qrow =
            Qh + ((size_t)bh * NTOK + qw + mt * 16 + l16) * HD + quad * 8;
        #pragma unroll
        for (int dk = 0; dk < 4; ++dk) qf[mt][dk] = *(const short8*)(qrow + dk * 32);
    }

    float m_r[2][4], l_r[2][4];
    f32x4 oac[8][2];
    #pragma unroll
    for (int mt = 0; mt < 2; ++mt)
        #pragma unroll
        for (int r = 0; r < 4; ++r) { m_r[mt][r] = -1e30f; l_r[mt][r] = 0.f; }
    #pragma unroll
    for (int md = 0; md < 8; ++md)
        #pragma unroll
        for (int nt = 0; nt < 2; ++nt) oac[md][nt] = (f32x4){0.f, 0.f, 0.f, 0.f};

    const float cscale = 0.08838834764831845f * 1.44269504088896f;

    // staging swizzle indices (see derivation in journal):
    int jrowK = wv * 4 + (lane >> 4);            // 0..15 (+ it*16)
    int cK = (lane & 15) ^ jrowK;                // global chunk for K
    int dV = wv * 8 + (lane >> 3);               // 0..31 (+ it*32)
    int cV = (lane & 7) ^ (lane >> 3);           // global chunk for Vt

    for (int j0 = 0; j0 < NTOK; j0 += 64) {
        #pragma unroll
        for (int it = 0; it < 4; ++it)
            GLOAD16(Kbh + (size_t)(j0 + it * 16 + jrowK) * HD + cK * 8,
                    &k_lds[(it * 256 + wv * 64) * 8]);
        #pragma unroll
        for (int it = 0; it < 4; ++it)
            GLOAD16(Vbh + (size_t)(it * 32 + dV) * NTOK + j0 + cV * 8,
                    &v_lds[(it * 256 + wv * 64) * 8]);
        __syncthreads();

        // ---- S = Q K^T ----
        f32x4 s[2][4];
        #pragma unroll
        for (int n = 0; n < 4; ++n) {
            int jl = n * 16 + l16;
            f32x4 a0 = (f32x4){0.f, 0.f, 0.f, 0.f};
            f32x4 a1 = (f32x4){0.f, 0.f, 0.f, 0.f};
            #pragma unroll
            for (int dk = 0; dk < 4; ++dk) {
                short8 kf = *(const short8*)&k_lds[(jl * 16 + ((dk * 4 + quad) ^ l16)) * 8];
                a0 = __builtin_amdgcn_mfma_f32_16x16x32_bf16(qf[0][dk], kf, a0, 0, 0, 0);
                a1 = __builtin_amdgcn_mfma_f32_16x16x32_bf16(qf[1][dk], kf, a1, 0, 0, 0);
            }
            s[0][n] = a0; s[1][n] = a1;
        }

        // ---- online softmax (row q = mt*16 + quad*4 + r) ----
        float alpha[2][4], rs[2][4];
        #pragma unroll
        for (int mt = 0; mt < 2; ++mt) {
            #pragma unroll
            for (int r = 0; r < 4; ++r) {
                float t = fmaxf(fmaxf(s[mt][0][r], s[mt][1][r]),
                                fmaxf(s[mt][2][r], s[mt][3][r]));
                t = fmaxf(t, __shfl_xor(t, 1));
                t = fmaxf(t, __shfl_xor(t, 2));
                t = fmaxf(t, __shfl_xor(t, 4));
                t = fmaxf(t, __shfl_xor(t, 8));
                float mn = fmaxf(m_r[mt][r], t * cscale);
                alpha[mt][r] = exp2f(m_r[mt][r] - mn);
                m_r[mt][r] = mn;
                rs[mt][r] = 0.f;
            }
        }

        // P = exp2(S*cscale - m): write row-major P[q][j] per wave
        #pragma unroll
        for (int mt = 0; mt < 2; ++mt)
            #pragma unroll
            for (int n = 0; n < 4; ++n) {
                #pragma unroll
                for (int r = 0; r < 4; ++r) {
                    float e = exp2f(s[mt][n][r] * cscale - m_r[mt][r]);
                    rs[mt][r] += e;
                    p_lds[wv][mt * 16 + quad * 4 + r][n * 16 + l16] = f2bfu(e);
                }
            }
        #pragma unroll
        for (int mt = 0; mt < 2; ++mt)
            #pragma unroll
            for (int r = 0; r < 4; ++r) {
                float t = rs[mt][r];
                t += __shfl_xor(t, 1);
                t += __shfl_xor(t, 2);
                t += __shfl_xor(t, 4);
                t += __shfl_xor(t, 8);
                l_r[mt][r] = l_r[mt][r] * alpha[mt][r] + t;
            }

        // broadcast alpha to per-lane (q = nt*16 + l16)
        if (l16 == 0) {
            #pragma unroll
            for (int mt = 0; mt < 2; ++mt)
                #pragma unroll
                for (int r = 0; r < 4; ++r)
                    bc[wv][mt * 16 + quad * 4 + r] = alpha[mt][r];
        }
        float al[2];
        #pragma unroll
        for (int nt = 0; nt < 2; ++nt) al[nt] = bc[wv][nt * 16 + l16];
        #pragma unroll
        for (int md = 0; md < 8; ++md)
            #pragma unroll
            for (int nt = 0; nt < 2; ++nt) {
                oac[md][nt][0] *= al[nt]; oac[md][nt][1] *= al[nt];
                oac[md][nt][2] *= al[nt]; oac[md][nt][3] *= al[nt];
            }

        // ---- O^T += V^T P^T ----
        #pragma unroll
        for (int kt = 0; kt < 2; ++kt) {
            short8 pf[2];
            #pragma unroll
            for (int nt = 0; nt < 2; ++nt)
                pf[nt] = *(const short8*)&p_lds[wv][nt * 16 + l16][kt * 32 + quad * 8];
            #pragma unroll
            for (int md = 0; md < 8; ++md) {
                int dl = md * 16 + l16;
                short8 vf = *(const short8*)&v_lds[(dl * 8 + ((kt * 4 + quad) ^ (l16 & 7))) * 8];
                #pragma unroll
                for (int nt = 0; nt < 2; ++nt)
                    oac[md][nt] = __builtin_amdgcn_mfma_f32_16x16x32_bf16(
                        vf, pf[nt], oac[md][nt], 0, 0, 0);
            }
        }
        __syncthreads();
    }

    // ---- epilogue: O^T C-layout -> O[b][p][h*HD+d], 8B packed stores ----
    if (l16 == 0) {
        #pragma unroll
        for (int mt = 0; mt < 2; ++mt)
            #pragma unroll
            for (int r = 0; r < 4; ++r)
                bc[wv][mt * 16 + quad * 4 + r] = l_r[mt][r];
    }
    float il[2];
    #pragma unroll
    for (int nt = 0; nt < 2; ++nt) il[nt] = 1.0f / bc[wv][nt * 16 + l16];

    #pragma unroll
    for (int md = 0; md < 8; ++md)
        #pragma unroll
        for (int nt = 0; nt < 2; ++nt) {
            int q = qw + nt * 16 + l16;
            union { unsigned short u[4]; uint2 v; } pk;
            #pragma unroll
            for (int r = 0; r < 4; ++r) pk.u[r] = f2bfu(oac[md][nt][r] * il[nt]);
            *(uint2*)((unsigned short*)O +
                      ((size_t)(b * NTOK) + q) * DIMC + h * HD + md * 16 + quad * 4) = pk.v;
        }
}

// ---------------------------------------------------------------------------
extern "C" void kernel_launch(void* const* d_in, const int* in_sizes, int n_in,
                              void* d_out, int out_size, void* d_ws, size_t ws_size,
                              hipStream_t stream)
{
    const float* input     = (const float*)d_in[0];
    const float* context   = (const float*)d_in[1];
    const float* W_qkv_in  = (const float*)d_in[2];
    const float* b_qkv_in  = (const float*)d_in[3];
    const float* W_qkv_ctx = (const float*)d_in[4];
    const float* b_qkv_ctx = (const float*)d_in[5];
    const float* qs_in     = (const float*)d_in[6];
    const float* ks_in     = (const float*)d_in[7];
    const float* qs_ctx    = (const float*)d_in[8];
    const float* ks_ctx    = (const float*)d_in[9];
    const float* W_out_in  = (const float*)d_in[10];
    const float* b_out_in  = (const float*)d_in[11];
    const float* W_out_ctx = (const float*)d_in[12];
    const float* b_out_ctx = (const float*)d_in[13];
    float* out = (float*)d_out;

    // workspace layout (total 127,401,984 B, same footprint as round 3/4)
    char* ws = (char*)d_ws;
    unsigned short* QKVb = (unsigned short*)ws;                    // [4608][4608] bf16
    bf16*           Ob   = (bf16*)ws;                              // [4608][1536] (QKVb dead)
    unsigned short* Qb   = (unsigned short*)(ws + 42467328);       // [2,12,2304,128]
    unsigned short* Kb   = Qb + (size_t)BATCH * NH * NTOK * HD;
    unsigned short* Vtb  = Kb + (size_t)BATCH * NH * NTOK * HD;    // [2,12,128,2304]
    unsigned short* AbIn  = (unsigned short*)(ws + 84934656);      // [4096][1536]
    unsigned short* AbCtx = AbIn + (size_t)BATCH * SIN * DIMC;
    unsigned short* WtOutIn  = (unsigned short*)(ws + 84934656);   // overlays Ab (dead by then)
    unsigned short* WtOutCtx = WtOutIn + (size_t)DIMC * DIMC;
    unsigned short* WtQkvIn  = (unsigned short*)(ws + 99090432);   // [4608][1536]
    unsigned short* WtQkvCtx = (unsigned short*)(ws + 113246208);  // [4608][1536]

    // --- convert activations + QKV weights ---
    cvt_bf16<<<(BATCH * SIN * DIMC / 4 + 255) / 256, 256, 0, stream>>>(
        input, AbIn, BATCH * SIN * DIMC / 4);
    cvt_bf16<<<(BATCH * SCTX * DIMC / 4 + 255) / 256, 256, 0, stream>>>(
        context, AbCtx, BATCH * SCTX * DIMC / 4);
    transpose_cvt<<<dim3(NQKV / 32, DIMC / 32), 256, 0, stream>>>(W_qkv_in, WtQkvIn, DIMC, NQKV);
    transpose_cvt<<<dim3(NQKV / 32, DIMC / 32), 256, 0, stream>>>(W_qkv_ctx, WtQkvCtx, DIMC, NQKV);

    // --- QKV projections (bf16 C, scatter into combined ctx-first order) ---
    gemm_mfma<unsigned short><<<dim3(NQKV / 128, (BATCH * SIN) / 128), 256, 0, stream>>>(
        AbIn, WtQkvIn, b_qkv_in, QKVb, NQKV, DIMC, SIN, SIN, 0, NTOK, SCTX);
    gemm_mfma<unsigned short><<<dim3(NQKV / 128, (BATCH * SCTX) / 128), 256, 0, stream>>>(
        AbCtx, WtQkvCtx, b_qkv_ctx, QKVb, NQKV, DIMC, SCTX, SCTX, 0, NTOK, 0);

    // --- RMS norm + RoPE (Q,K) and V transpose ---
    rms_rope_pack<<<BATCH * NTOK, 256, 0, stream>>>(
        QKVb, qs_in, ks_in, qs_ctx, ks_ctx, (bf16*)Qb, (bf16*)Kb);
    vt_pack<<<BATCH * NH * (NTOK / 64), 256, 0, stream>>>(QKVb, Vtb);

    // --- attention (bf16 O over dead QKVb region) ---
    attn_mfma<<<BATCH * NH * (NTOK / 128), 256, 0, stream>>>(Qb, Kb, Vtb, Ob);

    // --- out-proj weights (into dead Ab region), then projections (fp32 C) ---
    transpose_cvt<<<dim3(DIMC / 32, DIMC / 32), 256, 0, stream>>>(W_out_in, WtOutIn, DIMC, DIMC);
    transpose_cvt<<<dim3(DIMC / 32, DIMC / 32), 256, 0, stream>>>(W_out_ctx, WtOutCtx, DIMC, DIMC);

    gemm_mfma<float><<<dim3(DIMC / 128, (BATCH * SIN) / 128), 256, 0, stream>>>(
        (const unsigned short*)Ob, WtOutIn, b_out_in, out,
        DIMC, DIMC, SIN, NTOK, SCTX, SIN, 0);
    gemm_mfma<float><<<dim3(DIMC / 128, (BATCH * SCTX) / 128), 256, 0, stream>>>(
        (const unsigned short*)Ob, WtOutCtx, b_out_ctx, out + (size_t)BATCH * SIN * DIMC,
        DIMC, DIMC, SCTX, NTOK, 0, SCTX, 0);
}